// Round 2
// baseline (694.919 us; speedup 1.0000x reference)
//
#include <hip/hip_runtime.h>
#include <hip/hip_bf16.h>

typedef __bf16 bf16x8 __attribute__((ext_vector_type(8)));
typedef float f32x4 __attribute__((ext_vector_type(4)));

#define TOKENS 8192
#define D_IN   4096
#define D_OUT  4096

// fp32 -> bf16 bits, round-to-nearest-even
static __device__ __forceinline__ unsigned short f2bf(float f) {
  union { float f; unsigned int u; } v; v.f = f;
  unsigned int r = v.u + 0x7FFFu + ((v.u >> 16) & 1u);
  return (unsigned short)(r >> 16);
}

// ---------------------------------------------------------------------------
// Kernel 1: ABt[o][f*64+k] = sum_r tanh(As[f,o,r]) * Bs[f,r,k]
// grid = 2*1024 blocks, 256 threads. Each block: one f, 4 o-rows.
// ---------------------------------------------------------------------------
__global__ void ab_kernel(const float* __restrict__ As,
                          const float* __restrict__ Bs,
                          float* __restrict__ ABt) {
  __shared__ float tA[4][64];
  __shared__ float sB[64][64];
  const int t = threadIdx.x;
  const int f = blockIdx.x >> 10;
  const int o0 = (blockIdx.x & 1023) * 4;
  const int ol = t >> 6;         // wave id = local o row (uniform per wave)
  const int k  = t & 63;         // lane
  tA[ol][k] = tanhf(As[((size_t)f * 4096 + o0 + ol) * 64 + k]);
#pragma unroll
  for (int j = 0; j < 16; ++j) {
    int e = t + 256 * j;
    sB[e >> 6][e & 63] = Bs[f * 4096 + e];
  }
  __syncthreads();
  float acc = 0.f;
#pragma unroll
  for (int r = 0; r < 64; ++r) acc += tA[ol][r] * sB[r][k];
  ABt[(size_t)(o0 + ol) * 128 + f * 64 + k] = acc;
}

// ---------------------------------------------------------------------------
// Kernel 2: Weff[o][i] = bf16( W[o][i] + sum_fk ABt[o][fk] * Cs[fk][i] )
// GEMM M=4096(o) N=4096(i) K=128. 64x64 tile per 256-thread block,
// each thread 4x4 outputs. fp32 VALU (only 4.3 GFLOP).
// grid = (64, 64): x -> i tile, y -> o tile.
// ---------------------------------------------------------------------------
__global__ void weff_kernel(const float* __restrict__ W,
                            const float* __restrict__ ABt,
                            const float* __restrict__ Cs,
                            unsigned short* __restrict__ Weff) {
  __shared__ float sA[64][129];  // [o][k], padded
  __shared__ float sB[32][64];   // [k][i]
  const int t = threadIdx.x;
  const int i0 = blockIdx.x * 64;
  const int o0 = blockIdx.y * 64;
  // stage all A rows for this o-tile: 64 x 128 fp32
#pragma unroll
  for (int j = 0; j < 32; ++j) {
    int e = t + 256 * j;                       // 0..8191
    sA[e >> 7][e & 127] = ABt[(size_t)(o0 + (e >> 7)) * 128 + (e & 127)];
  }
  const int tx = t & 15, ty = t >> 4;
  float acc[4][4] = {};
  for (int kc = 0; kc < 128; kc += 32) {
    __syncthreads();                            // covers sA stage + sB reuse
#pragma unroll
    for (int j = 0; j < 8; ++j) {
      int e = t + 256 * j;                      // 0..2047
      sB[e >> 6][e & 63] = Cs[(size_t)(kc + (e >> 6)) * D_IN + i0 + (e & 63)];
    }
    __syncthreads();
#pragma unroll
    for (int k = 0; k < 32; ++k) {
      float4 b = *(const float4*)&sB[k][tx * 4];
#pragma unroll
      for (int r = 0; r < 4; ++r) {
        float a = sA[ty * 4 + r][kc + k];
        acc[r][0] += a * b.x;
        acc[r][1] += a * b.y;
        acc[r][2] += a * b.z;
        acc[r][3] += a * b.w;
      }
    }
  }
#pragma unroll
  for (int r = 0; r < 4; ++r) {
    const int o = o0 + ty * 4 + r;
    const float4 w = *(const float4*)&W[(size_t)o * D_IN + i0 + tx * 4];
    union { unsigned short h[4]; uint2 u; } p;
    p.h[0] = f2bf(w.x + acc[r][0]);
    p.h[1] = f2bf(w.y + acc[r][1]);
    p.h[2] = f2bf(w.z + acc[r][2]);
    p.h[3] = f2bf(w.w + acc[r][3]);
    *(uint2*)(Weff + (size_t)o * D_IN + i0 + tx * 4) = p.u;
  }
}

// ---------------------------------------------------------------------------
// Kernel 3: cast x (fp32) -> bf16, 8 elems/thread
// ---------------------------------------------------------------------------
__global__ void cast_kernel(const float* __restrict__ x,
                            unsigned short* __restrict__ xb) {
  size_t i = ((size_t)blockIdx.x * 256 + threadIdx.x) * 8;
  float4 a = *(const float4*)(x + i);
  float4 b = *(const float4*)(x + i + 4);
  union { unsigned short h[8]; uint4 u; } p;
  p.h[0] = f2bf(a.x); p.h[1] = f2bf(a.y);
  p.h[2] = f2bf(a.z); p.h[3] = f2bf(a.w);
  p.h[4] = f2bf(b.x); p.h[5] = f2bf(b.y);
  p.h[6] = f2bf(b.z); p.h[7] = f2bf(b.w);
  *(uint4*)(xb + i) = p.u;
}

// ---------------------------------------------------------------------------
// Kernel 4: main GEMM  C[m][n] = sum_k A[m][k]*B[n][k] + bias[n]
// A = x_bf16 [8192][4096], B = Weff_bf16 [4096][4096] (B^T layout)
// m97 structure: 128x128 tile, BK=64, 256 thr = 4 waves (2x2 of 64x64),
// each wave 4x4 of 16x16x32 MFMA. global_load_lds width=16 staging.
// grid = (N/128=32, M/128=64)
// ---------------------------------------------------------------------------
__global__ __launch_bounds__(256) void gemm_kernel(
    const unsigned short* __restrict__ Abf,
    const unsigned short* __restrict__ Bbf,
    const float* __restrict__ bias,
    float* __restrict__ C) {
  const int K = D_IN, N = D_OUT;
  __shared__ __align__(16) unsigned short sA[128 * 64];  // 16 KB, row-major [m][k]
  __shared__ __align__(16) unsigned short sB[128 * 64];  // 16 KB, row-major [n][k]
  const int t = threadIdx.x;
  const int lane = t & 63;
  const int wave = t >> 6;
  const int bn = blockIdx.x, bm = blockIdx.y;
  const int wm = (wave & 1) * 64, wn = (wave >> 1) * 64;

  // staging: thread t loads rows (t>>3) + j*32, cols (t&7)*8 .. +8  (16 B)
  // LDS dest byte offset = j*4096 + t*16  -> exactly wave-contiguous order
  const unsigned short* ag = Abf + (size_t)(bm * 128 + (t >> 3)) * K + (t & 7) * 8;
  const unsigned short* bg = Bbf + (size_t)(bn * 128 + (t >> 3)) * K + (t & 7) * 8;
  unsigned short* la = sA + t * 8;
  unsigned short* lb = sB + t * 8;

  f32x4 acc[4][4] = {};
  const int lm = lane & 15;           // A/B fragment row (m or n within 16-tile)
  const int kq = (lane >> 4) * 8;     // k-chunk within 32

  for (int kt = 0; kt < K; kt += 64) {
    __syncthreads();  // previous tile fully consumed
#pragma unroll
    for (int j = 0; j < 4; ++j) {
      __builtin_amdgcn_global_load_lds(
          (const __attribute__((address_space(1))) void*)(ag + (size_t)j * 32 * K + kt),
          (__attribute__((address_space(3))) void*)(la + j * 2048), 16, 0, 0);
      __builtin_amdgcn_global_load_lds(
          (const __attribute__((address_space(1))) void*)(bg + (size_t)j * 32 * K + kt),
          (__attribute__((address_space(3))) void*)(lb + j * 2048), 16, 0, 0);
    }
    __syncthreads();  // drains vmcnt before compute
#pragma unroll
    for (int ks = 0; ks < 2; ++ks) {
      bf16x8 af[4], bfr[4];
#pragma unroll
      for (int mi = 0; mi < 4; ++mi)
        af[mi] = *(const bf16x8*)(sA + (wm + mi * 16 + lm) * 64 + ks * 32 + kq);
#pragma unroll
      for (int ni = 0; ni < 4; ++ni)
        bfr[ni] = *(const bf16x8*)(sB + (wn + ni * 16 + lm) * 64 + ks * 32 + kq);
#pragma unroll
      for (int mi = 0; mi < 4; ++mi)
#pragma unroll
        for (int ni = 0; ni < 4; ++ni)
          acc[mi][ni] = __builtin_amdgcn_mfma_f32_16x16x32_bf16(
              af[mi], bfr[ni], acc[mi][ni], 0, 0, 0);
    }
  }

  // epilogue: C/D layout col = lane&15, row = (lane>>4)*4 + reg
  const int cn = lane & 15;
  const int rm = (lane >> 4) * 4;
#pragma unroll
  for (int ni = 0; ni < 4; ++ni) {
    const int col = bn * 128 + wn + ni * 16 + cn;
    const float bv = bias[col];
#pragma unroll
    for (int mi = 0; mi < 4; ++mi) {
      const int row0 = bm * 128 + wm + mi * 16 + rm;
#pragma unroll
      for (int r = 0; r < 4; ++r)
        C[(size_t)(row0 + r) * N + col] = acc[mi][ni][r] + bv;
    }
  }
}

// ---------------------------------------------------------------------------
extern "C" void kernel_launch(void* const* d_in, const int* in_sizes, int n_in,
                              void* d_out, int out_size, void* d_ws, size_t ws_size,
                              hipStream_t stream) {
  const float* x    = (const float*)d_in[0];  // [8192,4096]
  const float* W    = (const float*)d_in[1];  // [4096,4096]
  const float* bias = (const float*)d_in[2];  // [4096]
  const float* As   = (const float*)d_in[3];  // [2,4096,64]
  const float* Bs   = (const float*)d_in[4];  // [2,64,64]
  const float* Cs   = (const float*)d_in[5];  // [2,64,4096] -> flat [128,4096]
  float* out = (float*)d_out;                 // [8192,4096] fp32

  char* ws = (char*)d_ws;
  float* ABt           = (float*)ws;                                       // 2 MB
  unsigned short* Weff = (unsigned short*)(ws + (2u << 20));               // 32 MB
  unsigned short* xb   = (unsigned short*)(ws + (2u << 20) + (32u << 20)); // 64 MB

  ab_kernel<<<2048, 256, 0, stream>>>(As, Bs, ABt);
  weff_kernel<<<dim3(64, 64), 256, 0, stream>>>(W, ABt, Cs, Weff);
  cast_kernel<<<16384, 256, 0, stream>>>(x, xb);
  gemm_kernel<<<dim3(32, 64), 256, 0, stream>>>(xb, Weff, bias, out);
}

// Round 3
// 615.398 us; speedup vs baseline: 1.1292x; 1.1292x over previous
//
#include <hip/hip_runtime.h>
#include <hip/hip_bf16.h>

typedef __bf16 bf16x8 __attribute__((ext_vector_type(8)));
typedef float f32x4 __attribute__((ext_vector_type(4)));

#define TOKENS 8192
#define D_IN   4096
#define D_OUT  4096

// fp32 -> bf16 bits, round-to-nearest-even
static __device__ __forceinline__ unsigned short f2bf(float f) {
  union { float f; unsigned int u; } v; v.f = f;
  unsigned int r = v.u + 0x7FFFu + ((v.u >> 16) & 1u);
  return (unsigned short)(r >> 16);
}

// ---------------------------------------------------------------------------
// Kernel 1: ABt[o][f*64+k] = sum_r tanh(As[f,o,r]) * Bs[f,r,k]
// ---------------------------------------------------------------------------
__global__ void ab_kernel(const float* __restrict__ As,
                          const float* __restrict__ Bs,
                          float* __restrict__ ABt) {
  __shared__ float tA[4][64];
  __shared__ float sB[64][64];
  const int t = threadIdx.x;
  const int f = blockIdx.x >> 10;
  const int o0 = (blockIdx.x & 1023) * 4;
  const int ol = t >> 6;
  const int k  = t & 63;
  tA[ol][k] = tanhf(As[((size_t)f * 4096 + o0 + ol) * 64 + k]);
#pragma unroll
  for (int j = 0; j < 16; ++j) {
    int e = t + 256 * j;
    sB[e >> 6][e & 63] = Bs[f * 4096 + e];
  }
  __syncthreads();
  float acc = 0.f;
#pragma unroll
  for (int r = 0; r < 64; ++r) acc += tA[ol][r] * sB[r][k];
  ABt[(size_t)(o0 + ol) * 128 + f * 64 + k] = acc;
}

// ---------------------------------------------------------------------------
// Kernel 2: Weff[o][i] = bf16( W[o][i] + sum_fk ABt[o][fk] * Cs[fk][i] )
// ---------------------------------------------------------------------------
__global__ void weff_kernel(const float* __restrict__ W,
                            const float* __restrict__ ABt,
                            const float* __restrict__ Cs,
                            unsigned short* __restrict__ Weff) {
  __shared__ float sA[64][129];
  __shared__ float sB[32][64];
  const int t = threadIdx.x;
  const int i0 = blockIdx.x * 64;
  const int o0 = blockIdx.y * 64;
#pragma unroll
  for (int j = 0; j < 32; ++j) {
    int e = t + 256 * j;
    sA[e >> 7][e & 127] = ABt[(size_t)(o0 + (e >> 7)) * 128 + (e & 127)];
  }
  const int tx = t & 15, ty = t >> 4;
  float acc[4][4] = {};
  for (int kc = 0; kc < 128; kc += 32) {
    __syncthreads();
#pragma unroll
    for (int j = 0; j < 8; ++j) {
      int e = t + 256 * j;
      sB[e >> 6][e & 63] = Cs[(size_t)(kc + (e >> 6)) * D_IN + i0 + (e & 63)];
    }
    __syncthreads();
#pragma unroll
    for (int k = 0; k < 32; ++k) {
      float4 b = *(const float4*)&sB[k][tx * 4];
#pragma unroll
      for (int r = 0; r < 4; ++r) {
        float a = sA[ty * 4 + r][kc + k];
        acc[r][0] += a * b.x;
        acc[r][1] += a * b.y;
        acc[r][2] += a * b.z;
        acc[r][3] += a * b.w;
      }
    }
  }
#pragma unroll
  for (int r = 0; r < 4; ++r) {
    const int o = o0 + ty * 4 + r;
    const float4 w = *(const float4*)&W[(size_t)o * D_IN + i0 + tx * 4];
    union { unsigned short h[4]; uint2 u; } p;
    p.h[0] = f2bf(w.x + acc[r][0]);
    p.h[1] = f2bf(w.y + acc[r][1]);
    p.h[2] = f2bf(w.z + acc[r][2]);
    p.h[3] = f2bf(w.w + acc[r][3]);
    *(uint2*)(Weff + (size_t)o * D_IN + i0 + tx * 4) = p.u;
  }
}

// ---------------------------------------------------------------------------
// Kernel 3: cast x (fp32) -> bf16, 8 elems/thread
// ---------------------------------------------------------------------------
__global__ void cast_kernel(const float* __restrict__ x,
                            unsigned short* __restrict__ xb) {
  size_t i = ((size_t)blockIdx.x * 256 + threadIdx.x) * 8;
  float4 a = *(const float4*)(x + i);
  float4 b = *(const float4*)(x + i + 4);
  union { unsigned short h[8]; uint4 u; } p;
  p.h[0] = f2bf(a.x); p.h[1] = f2bf(a.y);
  p.h[2] = f2bf(a.z); p.h[3] = f2bf(a.w);
  p.h[4] = f2bf(b.x); p.h[5] = f2bf(b.y);
  p.h[6] = f2bf(b.z); p.h[7] = f2bf(b.w);
  *(uint4*)(xb + i) = p.u;
}

// ---------------------------------------------------------------------------
// Kernel 4: main GEMM  C[m][n] = sum_k A[m][k]*B[n][k] + bias[n]
// 128x128 tile, BK=64, 4 waves, 4x4 of 16x16x32 MFMA each.
// LDS rows are 128 B (=32 banks), so 16-B chunks within each row are
// XOR-swizzled by (row&7) to kill the 16-way ds_read_b128 bank conflict
// (R2 counters: SQ_LDS_BANK_CONFLICT=1.0e8 = ~38% of kernel cycles).
// Swizzle is applied on the GLOBAL side of global_load_lds (LDS dest is
// pinned to lane*16B) and undone at fragment-read time.
// ---------------------------------------------------------------------------
__global__ __launch_bounds__(256) void gemm_kernel(
    const unsigned short* __restrict__ Abf,
    const unsigned short* __restrict__ Bbf,
    const float* __restrict__ bias,
    float* __restrict__ C) {
  const int K = D_IN, N = D_OUT;
  __shared__ __align__(16) unsigned short sA[128 * 64];  // 16 KB [m][k-swizzled]
  __shared__ __align__(16) unsigned short sB[128 * 64];  // 16 KB [n][k-swizzled]
  const int t = threadIdx.x;
  const int lane = t & 63;
  const int wave = t >> 6;
  const int bn = blockIdx.x, bm = blockIdx.y;
  const int wm = (wave & 1) * 64, wn = (wave >> 1) * 64;

  // staging: thread t covers row (t>>3)+j*32, global 16B chunk (t&7)^(row&7).
  // (row&7) == ((t>>3)&7) is invariant under the +32 row step.
  const int r8 = (t >> 3) & 7;
  const int cg = (t & 7) ^ r8;   // swizzled global chunk index
  const unsigned short* ag = Abf + (size_t)(bm * 128 + (t >> 3)) * K + cg * 8;
  const unsigned short* bg = Bbf + (size_t)(bn * 128 + (t >> 3)) * K + cg * 8;
  unsigned short* la = sA + t * 8;
  unsigned short* lb = sB + t * 8;

  f32x4 acc[4][4] = {};
  const int lm = lane & 15;      // fragment row within 16-tile
  const int cb = lane >> 4;      // k-chunk 0..3 within ks-half
  const int sw = lm & 7;         // row swizzle key

  for (int kt = 0; kt < K; kt += 64) {
    __syncthreads();  // previous tile fully consumed
#pragma unroll
    for (int j = 0; j < 4; ++j) {
      __builtin_amdgcn_global_load_lds(
          (const __attribute__((address_space(1))) void*)(ag + (size_t)j * 32 * K + kt),
          (__attribute__((address_space(3))) void*)(la + j * 2048), 16, 0, 0);
      __builtin_amdgcn_global_load_lds(
          (const __attribute__((address_space(1))) void*)(bg + (size_t)j * 32 * K + kt),
          (__attribute__((address_space(3))) void*)(lb + j * 2048), 16, 0, 0);
    }
    __syncthreads();  // drains vmcnt before compute
#pragma unroll
    for (int ks = 0; ks < 2; ++ks) {
      const int ch = ((ks * 4 + cb) ^ sw) * 8;  // swizzled element offset in row
      bf16x8 af[4], bfr[4];
#pragma unroll
      for (int mi = 0; mi < 4; ++mi)
        af[mi] = *(const bf16x8*)(sA + (wm + mi * 16 + lm) * 64 + ch);
#pragma unroll
      for (int ni = 0; ni < 4; ++ni)
        bfr[ni] = *(const bf16x8*)(sB + (wn + ni * 16 + lm) * 64 + ch);
#pragma unroll
      for (int mi = 0; mi < 4; ++mi)
#pragma unroll
        for (int ni = 0; ni < 4; ++ni)
          acc[mi][ni] = __builtin_amdgcn_mfma_f32_16x16x32_bf16(
              af[mi], bfr[ni], acc[mi][ni], 0, 0, 0);
    }
  }

  // epilogue: C/D layout col = lane&15, row = (lane>>4)*4 + reg
  const int cn = lane & 15;
  const int rm = (lane >> 4) * 4;
#pragma unroll
  for (int ni = 0; ni < 4; ++ni) {
    const int col = bn * 128 + wn + ni * 16 + cn;
    const float bv = bias[col];
#pragma unroll
    for (int mi = 0; mi < 4; ++mi) {
      const int row0 = bm * 128 + wm + mi * 16 + rm;
#pragma unroll
      for (int r = 0; r < 4; ++r)
        C[(size_t)(row0 + r) * N + col] = acc[mi][ni][r] + bv;
    }
  }
}

// ---------------------------------------------------------------------------
extern "C" void kernel_launch(void* const* d_in, const int* in_sizes, int n_in,
                              void* d_out, int out_size, void* d_ws, size_t ws_size,
                              hipStream_t stream) {
  const float* x    = (const float*)d_in[0];  // [8192,4096]
  const float* W    = (const float*)d_in[1];  // [4096,4096]
  const float* bias = (const float*)d_in[2];  // [4096]
  const float* As   = (const float*)d_in[3];  // [2,4096,64]
  const float* Bs   = (const float*)d_in[4];  // [2,64,64]
  const float* Cs   = (const float*)d_in[5];  // [2,64,4096] -> flat [128,4096]
  float* out = (float*)d_out;                 // [8192,4096] fp32

  char* ws = (char*)d_ws;
  float* ABt           = (float*)ws;                                       // 2 MB
  unsigned short* Weff = (unsigned short*)(ws + (2u << 20));               // 32 MB
  unsigned short* xb   = (unsigned short*)(ws + (2u << 20) + (32u << 20)); // 64 MB

  ab_kernel<<<2048, 256, 0, stream>>>(As, Bs, ABt);
  weff_kernel<<<dim3(64, 64), 256, 0, stream>>>(W, ABt, Cs, Weff);
  cast_kernel<<<16384, 256, 0, stream>>>(x, xb);
  gemm_kernel<<<dim3(32, 64), 256, 0, stream>>>(xb, Weff, bias, out);
}